// Round 1
// baseline (658.417 us; speedup 1.0000x reference)
//
#include <hip/hip_runtime.h>

// ---- problem constants ----
constexpr int B_  = 128;
constexpr int T_  = 24;
constexpr int E_  = 512;
constexpr int H_  = 512;
constexpr int V_  = 10000;
constexpr int G4  = 2048;   // 4*H
constexpr int TP1 = 25;     // T+1

typedef __attribute__((ext_vector_type(8))) short bf16x8;   // 8 bf16 = 4 VGPR
typedef __attribute__((ext_vector_type(4))) short short4v;  // 4 bf16 = 8 B
typedef __attribute__((ext_vector_type(4))) float f32x4;

#define MFMA_16x16x32_BF16(a, b, c) __builtin_amdgcn_mfma_f32_16x16x32_bf16((a), (b), (c), 0, 0, 0)

// fp32 -> bf16 round-to-nearest-even (bit-level, no header ABI dependence)
__device__ inline unsigned short f2bf(float f) {
    unsigned int u = __float_as_uint(f);
    unsigned int r = (u + 0x7FFFu + ((u >> 16) & 1u)) >> 16;
    return (unsigned short)r;
}

// ---------------------------------------------------------------------------
// Bulk fp32 -> bf16 convert (float4 in, short4 out). n4 = elem_count/4.
// ---------------------------------------------------------------------------
__global__ __launch_bounds__(256) void k_cvt(const float* __restrict__ src,
                                             unsigned short* __restrict__ dst, int n4) {
    int i = blockIdx.x * 256 + threadIdx.x;
    if (i >= n4) return;
    float4 v = ((const float4*)src)[i];
    short4v o;
    o[0] = (short)f2bf(v.x); o[1] = (short)f2bf(v.y);
    o[2] = (short)f2bf(v.z); o[3] = (short)f2bf(v.w);
    ((short4v*)dst)[i] = o;
}

// ---------------------------------------------------------------------------
// Embedding gather -> bf16, padding_idx(0) -> zeros.
// Xemb[m][k], m = t*128 + b, 3072 rows x 512.
// ---------------------------------------------------------------------------
__global__ __launch_bounds__(256) void k_embed(const float* __restrict__ Wemb,
                                               const int* __restrict__ captions,
                                               unsigned short* __restrict__ Xemb) {
    int i = blockIdx.x * 256 + threadIdx.x;     // one thread per 4 elems
    if (i >= 3072 * 128) return;
    int row = i >> 7;                           // m = t*128 + b
    int k4  = i & 127;
    int b = row & 127, t = row >> 7;
    int tok = captions[b * T_ + t];
    short4v o = {0, 0, 0, 0};
    if (tok > 0 && tok < V_) {                  // tok==0 is padding -> zeros
        float4 v = ((const float4*)(Wemb + (long)tok * E_))[k4];
        o[0] = (short)f2bf(v.x); o[1] = (short)f2bf(v.y);
        o[2] = (short)f2bf(v.z); o[3] = (short)f2bf(v.w);
    }
    ((short4v*)Xemb)[(long)row * 128 + k4] = o;
}

// ---------------------------------------------------------------------------
// t=0 one-hot rows (fp32) + (captions_length - 1) tail
// Launched AFTER the recurrence so d_out can double as scratch for P.
// ---------------------------------------------------------------------------
__global__ __launch_bounds__(256) void k_start(float* __restrict__ out,
                                               const int* __restrict__ cap_len) {
    int idx = blockIdx.x * 256 + threadIdx.x;
    constexpr int Q  = V_ / 4;                  // 2500 float4 per row
    constexpr int NQ = B_ * Q;                  // 320000
    float4 zero = {0.f, 0.f, 0.f, 0.f};
    float4 one1 = {0.f, 1.f, 0.f, 0.f};         // one-hot at v=1
    for (int i = idx; i < NQ; i += gridDim.x * 256) {
        int b = i / Q;
        int q = i - b * Q;
        ((float4*)out)[(long)b * (TP1 * V_ / 4) + q] = (q == 0) ? one1 : zero;
    }
    if (idx < B_) {
        out[(size_t)B_ * TP1 * V_ + idx] = (float)(cap_len[idx] - 1);
    }
}

// ---------------------------------------------------------------------------
// Precompute P[m][n] = Xemb[m] . Wih[n] + bih[n] + bhh[n]   (fp32 out)
// M=3072 (48 tiles of 64), N=2048 (32 tiles of 64), K=512.
// 64x64 tile per wave, same structure as k_logits. 1536 waves / 4 = 384 blocks.
// ---------------------------------------------------------------------------
__global__ __launch_bounds__(256) void k_pregemm(const unsigned short* __restrict__ Xemb,
                                                 const unsigned short* __restrict__ Wih,
                                                 const float* __restrict__ bih,
                                                 const float* __restrict__ bhh,
                                                 float* __restrict__ P) {
    int wid = blockIdx.x * 4 + (threadIdx.x >> 6);   // 0..1535
    int MI = wid >> 5;        // 0..47
    int NI = wid & 31;        // 0..31
    int lane = threadIdx.x & 63;
    int lm = lane & 15, lq = lane >> 4;

    const short* As = (const short*)Xemb;
    const short* Bs = (const short*)Wih;

    f32x4 acc[4][4] = {};
    #pragma unroll
    for (int k0 = 0; k0 < 512; k0 += 32) {
        int ko = k0 + lq * 8;
        bf16x8 af[4], bfr[4];
        #pragma unroll
        for (int mi = 0; mi < 4; mi++)
            af[mi] = *(const bf16x8*)(As + (long)(MI * 64 + mi * 16 + lm) * 512 + ko);
        #pragma unroll
        for (int ni = 0; ni < 4; ni++)
            bfr[ni] = *(const bf16x8*)(Bs + (long)(NI * 64 + ni * 16 + lm) * 512 + ko);
        #pragma unroll
        for (int mi = 0; mi < 4; mi++)
            #pragma unroll
            for (int ni = 0; ni < 4; ni++)
                acc[mi][ni] = MFMA_16x16x32_BF16(af[mi], bfr[ni], acc[mi][ni]);
    }

    // per-lane bias for the 4 n-columns this lane writes
    float bias[4];
    #pragma unroll
    for (int ni = 0; ni < 4; ni++) {
        int n = NI * 64 + ni * 16 + lm;
        bias[ni] = bih[n] + bhh[n];
    }

    #pragma unroll
    for (int mi = 0; mi < 4; mi++) {
        #pragma unroll
        for (int r = 0; r < 4; r++) {
            int m = MI * 64 + mi * 16 + lq * 4 + r;
            #pragma unroll
            for (int ni = 0; ni < 4; ni++) {
                int n = NI * 64 + ni * 16 + lm;
                P[(long)m * G4 + n] = acc[mi][ni][r] + bias[ni];
            }
        }
    }
}

// ---------------------------------------------------------------------------
// Fused per-step kernel: gates = P_t + h_in @ Whh^T, then LSTM cell, write
// h (bf16, double-buffered) + Hall_t + c. One wave owns ONE (M-tile, h-group)
// and computes the 16x16 tiles of ALL FOUR gates at those h-columns, so
// i/f/g/o for each (b,h) sit in the same lane & register slot -> in-register
// cell math, zero cross-lane traffic, no gates buffer.
// Jobs: 8 M-tiles x 32 h-groups = 256 waves = 64 blocks.
// ---------------------------------------------------------------------------
__global__ __launch_bounds__(256) void k_step(const float* __restrict__ Pt,     // P + t*128*2048
                                              const unsigned short* __restrict__ h_in,
                                              const unsigned short* __restrict__ Whh,
                                              float* __restrict__ c,
                                              unsigned short* __restrict__ h_out,
                                              unsigned short* __restrict__ Hall_t,
                                              int t) {
    int wid  = blockIdx.x * 4 + (threadIdx.x >> 6);  // 0..255
    int lane = threadIdx.x & 63;
    int MI = wid >> 5;        // 0..7  (M-tile: rows MI*16..+16, m == b)
    int HG = wid & 31;        // 0..31 (h-columns HG*16..+16)
    int lm = lane & 15, lq = lane >> 4;
    int hcol = HG * 16 + lm;

    // hoisted loads: P (precomputed xW+bias) and c_prev — issue before the
    // MFMA chain so their latency hides under it.
    float pv[4][4];
    #pragma unroll
    for (int g = 0; g < 4; g++) {
        int n = g * 512 + hcol;
        #pragma unroll
        for (int r = 0; r < 4; r++) {
            int mm = MI * 16 + lq * 4 + r;           // mm == b
            pv[g][r] = Pt[(long)mm * G4 + n];
        }
    }
    float cp[4] = {0.f, 0.f, 0.f, 0.f};
    if (t != 0) {
        #pragma unroll
        for (int r = 0; r < 4; r++) {
            int b = MI * 16 + lq * 4 + r;
            cp[r] = c[b * H_ + hcol];
        }
    }

    const short* A = (const short*)h_in + (long)(MI * 16 + lm) * H_;
    const short* Bp[4];
    #pragma unroll
    for (int g = 0; g < 4; g++)
        Bp[g] = (const short*)Whh + (long)(g * 512 + hcol) * H_;

    f32x4 acc[4] = {};
    #pragma unroll
    for (int k0 = 0; k0 < H_; k0 += 32) {
        int ko = k0 + lq * 8;
        bf16x8 a = *(const bf16x8*)(A + ko);
        #pragma unroll
        for (int g = 0; g < 4; g++)
            acc[g] = MFMA_16x16x32_BF16(a, *(const bf16x8*)(Bp[g] + ko), acc[g]);
    }

    // cell: gate order i,f,g,o along the 4H axis (acc[0..3] = i,f,g,o)
    #pragma unroll
    for (int r = 0; r < 4; r++) {
        int b = MI * 16 + lq * 4 + r;
        int idx = b * H_ + hcol;
        float gi = acc[0][r] + pv[0][r];
        float gf = acc[1][r] + pv[1][r];
        float gg = acc[2][r] + pv[2][r];
        float go = acc[3][r] + pv[3][r];
        float si = 1.f / (1.f + expf(-gi));
        float sf = 1.f / (1.f + expf(-gf));
        float so = 1.f / (1.f + expf(-go));
        float cn = sf * cp[r] + si * tanhf(gg);
        float hn = so * tanhf(cn);
        c[idx] = cn;
        unsigned short hb = f2bf(hn);
        h_out[idx] = hb;
        Hall_t[idx] = hb;
    }
}

// ---------------------------------------------------------------------------
// Logits: Hall[3072,512](bf16) @ Wout_bf^T + b_out(f32) -> fp32 out[b][t+1][v]
// 64x64 tile per wave; m = t*128 + b.
// ---------------------------------------------------------------------------
__global__ __launch_bounds__(256) void k_logits(const unsigned short* __restrict__ Hall,
                                                const unsigned short* __restrict__ Wout,
                                                const float* __restrict__ bout,
                                                float* __restrict__ out) {
    constexpr int NTILES = 157;                  // ceil(10000/64)
    int wid = blockIdx.x * 4 + (threadIdx.x >> 6);
    if (wid >= 48 * NTILES) return;
    int MI = wid / NTILES;
    int NI = wid - MI * NTILES;
    int lane = threadIdx.x & 63;
    int lm = lane & 15, lq = lane >> 4;

    const short* As = (const short*)Hall;
    const short* Bs = (const short*)Wout;

    f32x4 acc[4][4] = {};
    for (int k0 = 0; k0 < 512; k0 += 32) {
        int ko = k0 + lq * 8;
        bf16x8 af[4], bfr[4];
        #pragma unroll
        for (int mi = 0; mi < 4; mi++)
            af[mi] = *(const bf16x8*)(As + (long)(MI * 64 + mi * 16 + lm) * 512 + ko);
        #pragma unroll
        for (int ni = 0; ni < 4; ni++) {
            int n = NI * 64 + ni * 16 + lm;
            if (n >= V_) n = V_ - 1;             // clamp: garbage cols never stored
            bfr[ni] = *(const bf16x8*)(Bs + (long)n * 512 + ko);
        }
        #pragma unroll
        for (int mi = 0; mi < 4; mi++)
            #pragma unroll
            for (int ni = 0; ni < 4; ni++)
                acc[mi][ni] = MFMA_16x16x32_BF16(af[mi], bfr[ni], acc[mi][ni]);
    }

    #pragma unroll
    for (int mi = 0; mi < 4; mi++) {
        #pragma unroll
        for (int r = 0; r < 4; r++) {
            int m = MI * 64 + mi * 16 + lq * 4 + r;  // m = t*128 + b
            int b = m & 127, t = m >> 7;
            float* orow = out + ((size_t)b * TP1 + t + 1) * V_;
            #pragma unroll
            for (int ni = 0; ni < 4; ni++) {
                int n = NI * 64 + ni * 16 + lm;
                if (n < V_) orow[n] = acc[mi][ni][r] + bout[n];
            }
        }
    }
}

// ---------------------------------------------------------------------------
extern "C" void kernel_launch(void* const* d_in, const int* in_sizes, int n_in,
                              void* d_out, int out_size, void* d_ws, size_t ws_size,
                              hipStream_t stream) {
    const float* images   = (const float*)d_in[0];
    const int*   captions = (const int*)d_in[1];
    const int*   cap_len  = (const int*)d_in[2];
    const float* Wemb     = (const float*)d_in[3];
    const float* Wih      = (const float*)d_in[4];
    const float* Whh      = (const float*)d_in[5];
    const float* bih      = (const float*)d_in[6];
    const float* bhh      = (const float*)d_in[7];
    const float* Wout     = (const float*)d_in[8];
    const float* bout     = (const float*)d_in[9];
    float* out = (float*)d_out;

    // workspace layout (offsets 256B-aligned)
    char* ws = (char*)d_ws;
    unsigned short* Wih_bf  = (unsigned short*)(ws);              //  2,097,152 B
    unsigned short* Whh_bf  = (unsigned short*)(ws + 2097152);    //  2,097,152 B
    unsigned short* Wout_bf = (unsigned short*)(ws + 4194304);    // 10,240,000 B
    unsigned short* Xemb    = (unsigned short*)(ws + 14434304);   //  3,145,728 B
    unsigned short* Hall    = (unsigned short*)(ws + 17580032);   //  3,145,728 B
    unsigned short* h0      = (unsigned short*)(ws + 20725760);   //    131,072 B
    unsigned short* h1      = (unsigned short*)(ws + 20856832);   //    131,072 B
    float*          cbuf    = (float*)(ws + 20987904);            //    262,144 B
    // P: 3072 x 2048 fp32 = 25,165,824 B. Prefer workspace; fall back to
    // using d_out as scratch (safe: k_start + k_logits run after the
    // recurrence and together rewrite every byte of out).
    constexpr size_t P_OFF  = 21250048;
    constexpr size_t WS_NEED = P_OFF + 25165824;   // 46,415,872
    float* P = (ws_size >= WS_NEED) ? (float*)(ws + P_OFF) : (float*)d_out;

    // fp32 -> bf16 weight staging + embedding gather
    k_cvt<<<1024, 256, 0, stream>>>(Wih,    Wih_bf,  G4 * E_ / 4);       // 262144
    k_cvt<<<1024, 256, 0, stream>>>(Whh,    Whh_bf,  G4 * H_ / 4);       // 262144
    k_cvt<<<5000, 256, 0, stream>>>(Wout,   Wout_bf, V_ * H_ / 4);       // 1280000
    k_cvt<<<  64, 256, 0, stream>>>(images, h0,      B_ * H_ / 4);       // 16384
    k_embed<<<1536, 256, 0, stream>>>(Wemb, captions, Xemb);

    // hoisted input GEMM: P = Xemb @ Wih^T + (bih + bhh), all 24 steps at once
    k_pregemm<<<384, 256, 0, stream>>>(Xemb, Wih_bf, bih, bhh, P);

    // serial recurrence: one fused kernel per step (GEMM K=512 + cell)
    for (int t = 0; t < T_; t++) {
        const unsigned short* hin  = (t & 1) ? h1 : h0;
        unsigned short*       hout = (t & 1) ? h0 : h1;
        k_step<<<64, 256, 0, stream>>>(P + (long)t * B_ * G4, hin, Whh_bf,
                                       cbuf, hout, Hall + (long)t * B_ * H_, t);
    }

    // t=0 one-hot rows + length tail (after recurrence: out may hold P scratch)
    k_start<<<1250, 256, 0, stream>>>(out, cap_len);

    // all logits in one shot (48*157 = 7536 wave-tiles / 4 = 1884 blocks)
    k_logits<<<1884, 256, 0, stream>>>(Hall, Wout_bf, bout, out);
}

// Round 2
// 491.442 us; speedup vs baseline: 1.3398x; 1.3398x over previous
//
#include <hip/hip_runtime.h>

// ---- problem constants ----
constexpr int B_  = 128;
constexpr int T_  = 24;
constexpr int E_  = 512;
constexpr int H_  = 512;
constexpr int V_  = 10000;
constexpr int G4  = 2048;   // 4*H
constexpr int TP1 = 25;     // T+1

typedef __attribute__((ext_vector_type(8))) short bf16x8;   // 8 bf16 = 4 VGPR
typedef __attribute__((ext_vector_type(4))) short short4v;  // 4 bf16 = 8 B
typedef __attribute__((ext_vector_type(4))) float f32x4;

#define MFMA_16x16x32_BF16(a, b, c) __builtin_amdgcn_mfma_f32_16x16x32_bf16((a), (b), (c), 0, 0, 0)

// fp32 -> bf16 round-to-nearest-even (bit-level, no header ABI dependence)
__device__ inline unsigned short f2bf(float f) {
    unsigned int u = __float_as_uint(f);
    unsigned int r = (u + 0x7FFFu + ((u >> 16) & 1u)) >> 16;
    return (unsigned short)r;
}

// ---------------------------------------------------------------------------
// Bulk fp32 -> bf16 convert (float4 in, short4 out). n4 = elem_count/4.
// ---------------------------------------------------------------------------
__global__ __launch_bounds__(256) void k_cvt(const float* __restrict__ src,
                                             unsigned short* __restrict__ dst, int n4) {
    int i = blockIdx.x * 256 + threadIdx.x;
    if (i >= n4) return;
    float4 v = ((const float4*)src)[i];
    short4v o;
    o[0] = (short)f2bf(v.x); o[1] = (short)f2bf(v.y);
    o[2] = (short)f2bf(v.z); o[3] = (short)f2bf(v.w);
    ((short4v*)dst)[i] = o;
}

// ---------------------------------------------------------------------------
// Embedding gather -> bf16, padding_idx(0) -> zeros.
// Xemb[m][k], m = t*128 + b, 3072 rows x 512.
// ---------------------------------------------------------------------------
__global__ __launch_bounds__(256) void k_embed(const float* __restrict__ Wemb,
                                               const int* __restrict__ captions,
                                               unsigned short* __restrict__ Xemb) {
    int i = blockIdx.x * 256 + threadIdx.x;     // one thread per 4 elems
    if (i >= 3072 * 128) return;
    int row = i >> 7;                           // m = t*128 + b
    int k4  = i & 127;
    int b = row & 127, t = row >> 7;
    int tok = captions[b * T_ + t];
    short4v o = {0, 0, 0, 0};
    if (tok > 0 && tok < V_) {                  // tok==0 is padding -> zeros
        float4 v = ((const float4*)(Wemb + (long)tok * E_))[k4];
        o[0] = (short)f2bf(v.x); o[1] = (short)f2bf(v.y);
        o[2] = (short)f2bf(v.z); o[3] = (short)f2bf(v.w);
    }
    ((short4v*)Xemb)[(long)row * 128 + k4] = o;
}

// ---------------------------------------------------------------------------
// t=0 one-hot rows (fp32) + (captions_length - 1) tail
// Launched AFTER the recurrence so d_out can double as scratch for P.
// ---------------------------------------------------------------------------
__global__ __launch_bounds__(256) void k_start(float* __restrict__ out,
                                               const int* __restrict__ cap_len) {
    int idx = blockIdx.x * 256 + threadIdx.x;
    constexpr int Q  = V_ / 4;                  // 2500 float4 per row
    constexpr int NQ = B_ * Q;                  // 320000
    float4 zero = {0.f, 0.f, 0.f, 0.f};
    float4 one1 = {0.f, 1.f, 0.f, 0.f};         // one-hot at v=1
    for (int i = idx; i < NQ; i += gridDim.x * 256) {
        int b = i / Q;
        int q = i - b * Q;
        ((float4*)out)[(long)b * (TP1 * V_ / 4) + q] = (q == 0) ? one1 : zero;
    }
    if (idx < B_) {
        out[(size_t)B_ * TP1 * V_ + idx] = (float)(cap_len[idx] - 1);
    }
}

// ---------------------------------------------------------------------------
// Precompute P[m][n] = Xemb[m] . Wih[n] + bih[n] + bhh[n]   (fp32 out)
// M=3072 (48 tiles of 64), N=2048 (32 tiles of 64), K=512.
// XCD-swizzled: xcd = bid&7 owns NI chunk of 4 columns; MI-major within chunk
// so the B-panel (64 KB) stays hot in that XCD's L2. 384 blocks, exact cover.
// ---------------------------------------------------------------------------
__global__ __launch_bounds__(256) void k_pregemm(const unsigned short* __restrict__ Xemb,
                                                 const unsigned short* __restrict__ Wih,
                                                 const float* __restrict__ bih,
                                                 const float* __restrict__ bhh,
                                                 float* __restrict__ P) {
    int bid = blockIdx.x;                       // 0..383
    int w   = threadIdx.x >> 6;
    int xcd = bid & 7;
    int q   = (bid >> 3) * 4 + w;               // 0..191 within-XCD wave index
    int MI  = q % 48;                           // consecutive waves share NI
    int NI  = xcd * 4 + q / 48;                 // 0..31
    int lane = threadIdx.x & 63;
    int lm = lane & 15, lq = lane >> 4;

    const short* As = (const short*)Xemb;
    const short* Bs = (const short*)Wih;

    f32x4 acc[4][4] = {};
    for (int k0 = 0; k0 < 512; k0 += 32) {
        int ko = k0 + lq * 8;
        bf16x8 af[4], bfr[4];
        #pragma unroll
        for (int mi = 0; mi < 4; mi++)
            af[mi] = *(const bf16x8*)(As + (long)(MI * 64 + mi * 16 + lm) * 512 + ko);
        #pragma unroll
        for (int ni = 0; ni < 4; ni++)
            bfr[ni] = *(const bf16x8*)(Bs + (long)(NI * 64 + ni * 16 + lm) * 512 + ko);
        #pragma unroll
        for (int mi = 0; mi < 4; mi++)
            #pragma unroll
            for (int ni = 0; ni < 4; ni++)
                acc[mi][ni] = MFMA_16x16x32_BF16(af[mi], bfr[ni], acc[mi][ni]);
    }

    float bias[4];
    #pragma unroll
    for (int ni = 0; ni < 4; ni++) {
        int n = NI * 64 + ni * 16 + lm;
        bias[ni] = bih[n] + bhh[n];
    }

    #pragma unroll
    for (int mi = 0; mi < 4; mi++) {
        #pragma unroll
        for (int r = 0; r < 4; r++) {
            int m = MI * 64 + mi * 16 + lq * 4 + r;
            #pragma unroll
            for (int ni = 0; ni < 4; ni++) {
                int n = NI * 64 + ni * 16 + lm;
                P[(long)m * G4 + n] = acc[mi][ni][r] + bias[ni];
            }
        }
    }
}

// ---------------------------------------------------------------------------
// Fused per-step kernel, K-split x4 for parallelism:
// job = (MI 0..7, HG 0..31) -> one block of 4 waves. Wave w computes a K=128
// slice of all four gate tiles; LDS reduce ([16][4][64] fp32, lane-contiguous
// => conflict-free); wave 0 adds P + c_prev and does the LSTM cell in-register.
// 256 blocks x 4 waves = 1024 waves over all 256 CUs.
// ---------------------------------------------------------------------------
__global__ __launch_bounds__(256) void k_step(const float* __restrict__ Pt,     // P + t*128*2048
                                              const unsigned short* __restrict__ h_in,
                                              const unsigned short* __restrict__ Whh,
                                              float* __restrict__ c,
                                              unsigned short* __restrict__ h_out,
                                              unsigned short* __restrict__ Hall_t,
                                              int t) {
    __shared__ float part[16][4][64];            // [g*4+r][wave][lane]
    int w    = threadIdx.x >> 6;                 // 0..3 (K-slice)
    int lane = threadIdx.x & 63;
    int MI = blockIdx.x >> 5;                    // 0..7  (batch rows MI*16..+16)
    int HG = blockIdx.x & 31;                    // 0..31 (h-cols HG*16..+16)
    int lm = lane & 15, lq = lane >> 4;
    int hcol = HG * 16 + lm;

    // wave 0 prefetches P (xW+bias) and c_prev; latency hides under MFMA
    float pv[4][4];
    float cp[4] = {0.f, 0.f, 0.f, 0.f};
    if (w == 0) {
        #pragma unroll
        for (int g = 0; g < 4; g++) {
            int n = g * 512 + hcol;
            #pragma unroll
            for (int r = 0; r < 4; r++)
                pv[g][r] = Pt[(long)(MI * 16 + lq * 4 + r) * G4 + n];
        }
        if (t != 0) {
            #pragma unroll
            for (int r = 0; r < 4; r++)
                cp[r] = c[(MI * 16 + lq * 4 + r) * H_ + hcol];
        }
    }

    // K-slice GEMM: this wave covers k in [w*128, w*128+128)
    int ks = w * 128;
    const short* A = (const short*)h_in + (long)(MI * 16 + lm) * H_ + ks;
    const short* Bp[4];
    #pragma unroll
    for (int g = 0; g < 4; g++)
        Bp[g] = (const short*)Whh + (long)(g * 512 + hcol) * H_ + ks;

    f32x4 acc[4] = {};
    #pragma unroll
    for (int kk = 0; kk < 4; kk++) {
        int ko = kk * 32 + lq * 8;
        bf16x8 a = *(const bf16x8*)(A + ko);
        #pragma unroll
        for (int g = 0; g < 4; g++)
            acc[g] = MFMA_16x16x32_BF16(a, *(const bf16x8*)(Bp[g] + ko), acc[g]);
    }

    // partials (waves 1..3) -> LDS, lane-contiguous = conflict-free
    if (w != 0) {
        #pragma unroll
        for (int g = 0; g < 4; g++)
            #pragma unroll
            for (int r = 0; r < 4; r++)
                part[g * 4 + r][w][lane] = acc[g][r];
    }
    __syncthreads();

    if (w == 0) {
        // reduce + cell, all in-register per lane
        #pragma unroll
        for (int r = 0; r < 4; r++) {
            int b = MI * 16 + lq * 4 + r;
            int idx = b * H_ + hcol;
            float gi = acc[0][r] + part[0*4+r][1][lane] + part[0*4+r][2][lane] + part[0*4+r][3][lane] + pv[0][r];
            float gf = acc[1][r] + part[1*4+r][1][lane] + part[1*4+r][2][lane] + part[1*4+r][3][lane] + pv[1][r];
            float gg = acc[2][r] + part[2*4+r][1][lane] + part[2*4+r][2][lane] + part[2*4+r][3][lane] + pv[2][r];
            float go = acc[3][r] + part[3*4+r][1][lane] + part[3*4+r][2][lane] + part[3*4+r][3][lane] + pv[3][r];
            float si = 1.f / (1.f + expf(-gi));
            float sf = 1.f / (1.f + expf(-gf));
            float so = 1.f / (1.f + expf(-go));
            float cn = sf * cp[r] + si * tanhf(gg);
            float hn = so * tanhf(cn);
            c[idx] = cn;
            unsigned short hb = f2bf(hn);
            h_out[idx] = hb;
            Hall_t[idx] = hb;
        }
    }
}

// ---------------------------------------------------------------------------
// Logits: Hall[3072,512](bf16) @ Wout_bf^T + b_out(f32) -> fp32 out[b][t+1][v]
// 64x64 tile per wave; m = t*128 + b.
// XCD-swizzled: xcd = bid&7 owns NI chunk [xcd*20, +20) (last chunk 17), so
// the per-XCD working set (Hall 3 MB + B-chunk 1.25 MB) ~= its 4 MB L2.
// Within a chunk waves sweep MI-major: the 64 KB B-panel stays hot.
// Grid 1920 blocks; xcd 7's spare waves exit early.
// ---------------------------------------------------------------------------
__global__ __launch_bounds__(256) void k_logits(const unsigned short* __restrict__ Hall,
                                                const unsigned short* __restrict__ Wout,
                                                const float* __restrict__ bout,
                                                float* __restrict__ out) {
    int bid = blockIdx.x;                        // 0..1919
    int w   = threadIdx.x >> 6;
    int xcd = bid & 7;
    int q   = (bid >> 3) * 4 + w;                // within-XCD wave index, 0..959
    int cnt = (xcd == 7) ? 17 : 20;
    int MI  = q % 48;
    int NIl = q / 48;
    if (NIl >= cnt) return;
    int NI  = xcd * 20 + NIl;                    // 0..156
    int lane = threadIdx.x & 63;
    int lm = lane & 15, lq = lane >> 4;

    const short* As = (const short*)Hall;
    const short* Bs = (const short*)Wout;

    f32x4 acc[4][4] = {};
    for (int k0 = 0; k0 < 512; k0 += 32) {
        int ko = k0 + lq * 8;
        bf16x8 af[4], bfr[4];
        #pragma unroll
        for (int mi = 0; mi < 4; mi++)
            af[mi] = *(const bf16x8*)(As + (long)(MI * 64 + mi * 16 + lm) * 512 + ko);
        #pragma unroll
        for (int ni = 0; ni < 4; ni++) {
            int n = NI * 64 + ni * 16 + lm;
            if (n >= V_) n = V_ - 1;             // clamp: garbage cols never stored
            bfr[ni] = *(const bf16x8*)(Bs + (long)n * 512 + ko);
        }
        #pragma unroll
        for (int mi = 0; mi < 4; mi++)
            #pragma unroll
            for (int ni = 0; ni < 4; ni++)
                acc[mi][ni] = MFMA_16x16x32_BF16(af[mi], bfr[ni], acc[mi][ni]);
    }

    #pragma unroll
    for (int mi = 0; mi < 4; mi++) {
        #pragma unroll
        for (int r = 0; r < 4; r++) {
            int m = MI * 64 + mi * 16 + lq * 4 + r;  // m = t*128 + b
            int b = m & 127, t = m >> 7;
            float* orow = out + ((size_t)b * TP1 + t + 1) * V_;
            #pragma unroll
            for (int ni = 0; ni < 4; ni++) {
                int n = NI * 64 + ni * 16 + lm;
                if (n < V_) orow[n] = acc[mi][ni][r] + bout[n];
            }
        }
    }
}

// ---------------------------------------------------------------------------
extern "C" void kernel_launch(void* const* d_in, const int* in_sizes, int n_in,
                              void* d_out, int out_size, void* d_ws, size_t ws_size,
                              hipStream_t stream) {
    const float* images   = (const float*)d_in[0];
    const int*   captions = (const int*)d_in[1];
    const int*   cap_len  = (const int*)d_in[2];
    const float* Wemb     = (const float*)d_in[3];
    const float* Wih      = (const float*)d_in[4];
    const float* Whh      = (const float*)d_in[5];
    const float* bih      = (const float*)d_in[6];
    const float* bhh      = (const float*)d_in[7];
    const float* Wout     = (const float*)d_in[8];
    const float* bout     = (const float*)d_in[9];
    float* out = (float*)d_out;

    // workspace layout (offsets 256B-aligned)
    char* ws = (char*)d_ws;
    unsigned short* Wih_bf  = (unsigned short*)(ws);              //  2,097,152 B
    unsigned short* Whh_bf  = (unsigned short*)(ws + 2097152);    //  2,097,152 B
    unsigned short* Wout_bf = (unsigned short*)(ws + 4194304);    // 10,240,000 B
    unsigned short* Xemb    = (unsigned short*)(ws + 14434304);   //  3,145,728 B
    unsigned short* Hall    = (unsigned short*)(ws + 17580032);   //  3,145,728 B
    unsigned short* h0      = (unsigned short*)(ws + 20725760);   //    131,072 B
    unsigned short* h1      = (unsigned short*)(ws + 20856832);   //    131,072 B
    float*          cbuf    = (float*)(ws + 20987904);            //    262,144 B
    // P: 3072 x 2048 fp32 = 25,165,824 B. Prefer workspace; fall back to
    // using d_out as scratch (safe: k_start + k_logits run after the
    // recurrence and together rewrite every byte of out).
    constexpr size_t P_OFF  = 21250048;
    constexpr size_t WS_NEED = P_OFF + 25165824;   // 46,415,872
    float* P = (ws_size >= WS_NEED) ? (float*)(ws + P_OFF) : (float*)d_out;

    // fp32 -> bf16 weight staging + embedding gather
    k_cvt<<<1024, 256, 0, stream>>>(Wih,    Wih_bf,  G4 * E_ / 4);       // 262144
    k_cvt<<<1024, 256, 0, stream>>>(Whh,    Whh_bf,  G4 * H_ / 4);       // 262144
    k_cvt<<<5000, 256, 0, stream>>>(Wout,   Wout_bf, V_ * H_ / 4);       // 1280000
    k_cvt<<<  64, 256, 0, stream>>>(images, h0,      B_ * H_ / 4);       // 16384
    k_embed<<<1536, 256, 0, stream>>>(Wemb, captions, Xemb);

    // hoisted input GEMM: P = Xemb @ Wih^T + (bih + bhh), all 24 steps at once
    k_pregemm<<<384, 256, 0, stream>>>(Xemb, Wih_bf, bih, bhh, P);

    // serial recurrence: one fused kernel per step (K-split GEMM + cell)
    for (int t = 0; t < T_; t++) {
        const unsigned short* hin  = (t & 1) ? h1 : h0;
        unsigned short*       hout = (t & 1) ? h0 : h1;
        k_step<<<256, 256, 0, stream>>>(P + (long)t * B_ * G4, hin, Whh_bf,
                                        cbuf, hout, Hall + (long)t * B_ * H_, t);
    }

    // t=0 one-hot rows + length tail (after recurrence: out may hold P scratch)
    k_start<<<1250, 256, 0, stream>>>(out, cap_len);

    // all logits in one shot (XCD-swizzled, 1920 blocks)
    k_logits<<<1920, 256, 0, stream>>>(Hall, Wout_bf, bout, out);
}